// Round 10
// baseline (62.729 us; speedup 1.0000x reference)
//
#include <hip/hip_runtime.h>
#include <hip/hip_bf16.h>

#define DEVI static __device__ __forceinline__

typedef __attribute__((ext_vector_type(8))) short short8;
typedef __attribute__((ext_vector_type(16))) float f32x16;
typedef __attribute__((ext_vector_type(2))) unsigned int uintx2;

#define S_LEN 2048
#define D_DIM 128
#define NBATCH 16
// (1/sqrt(128)) * log2(e): base-2 softmax, scale folded into Q conversion
#define QSC ((float)(0.08838834764831845 * 1.4426950408889634))
// fixed softmax shift: P = 2^(score - 8); exact by shift-invariance
#define MFIX 8.0f
#define E8 0.00390625f  // 2^-8, weight of a masked (score 0) position

#if __has_builtin(__builtin_amdgcn_exp2f)
#define EXP2(x) __builtin_amdgcn_exp2f(x)
#else
#define EXP2(x) exp2f(x)
#endif

DEVI unsigned short f2bf(float x) {
  union { float f; unsigned int u; } a; a.f = x;
  unsigned int u = a.u;
  unsigned int r = (u + 0x7fffu + ((u >> 16) & 1u)) >> 16;
  return (unsigned short)r;
}

DEVI unsigned int cvtpk(float lo, float hi) {
  unsigned int r;
  asm volatile("v_cvt_pk_bf16_f32 %0, %1, %2" : "=v"(r) : "v"(lo), "v"(hi));
  return r;
}

// v_permlane32_swap_b32: post: a = {a.lo | b.lo}, b = {a.hi | b.hi}  (R4-verified)
DEVI void plswap(unsigned int& a, unsigned int& b) {
  uintx2 r = __builtin_amdgcn_permlane32_swap(a, b, false, false);
  a = r[0];
  b = r[1];
}

DEVI float xhalf_sum(float x) {
  union { float f; unsigned int u; } a, b;
  a.f = x; b.f = x;
  plswap(a.u, b.u);
  return a.f + b.f;
}

// ---------------- prepass ----------------

// blocks [0,1024): V [b][s][d] fp32 -> Vt TILE-MAJOR [b][kt][d 0..127][64 keys] bf16
//                  + per-64-row tile sums
// blocks [1024,3072): K fp32 -> bf16 (row-major unchanged)
__global__ void prep(const float* __restrict__ K, const float* __restrict__ V,
                     unsigned short* __restrict__ Kb, unsigned short* __restrict__ Vt,
                     float* __restrict__ Tsum) {
  __shared__ unsigned short t[64][68];
  const int tt = threadIdx.x;
  if (blockIdx.x >= 1024) {
    const int M4 = (NBATCH * S_LEN * D_DIM) / 4;
    for (int i = (blockIdx.x - 1024) * 256 + tt; i < M4; i += 2048 * 256) {
      const size_t idx = (size_t)i * 4;
      const float4 v = *reinterpret_cast<const float4*>(K + idx);
      ushort4 o;
      o.x = f2bf(v.x); o.y = f2bf(v.y); o.z = f2bf(v.z); o.w = f2bf(v.w);
      *reinterpret_cast<ushort4*>(Kb + idx) = o;
    }
    return;
  }
  const int bid = blockIdx.x;
  const int b = bid >> 6, rem = bid & 63;
  const int st = rem & 31, s0 = st * 64, d0 = (rem >> 5) * 64;
  const int r = tt >> 2, c = (tt & 3) * 16;
  const float* src = V + ((size_t)(b * S_LEN + s0 + r)) * D_DIM + d0 + c;
#pragma unroll
  for (int i = 0; i < 4; i++) {
    float4 v = reinterpret_cast<const float4*>(src)[i];
    t[r][c + 4 * i + 0] = f2bf(v.x);
    t[r][c + 4 * i + 1] = f2bf(v.y);
    t[r][c + 4 * i + 2] = f2bf(v.z);
    t[r][c + 4 * i + 3] = f2bf(v.w);
  }
  __syncthreads();
  // tile-major: Vt[((b*32+st)*128 + d)*64 + key]
  unsigned short* dst = Vt + (((size_t)(b * 32 + st)) * 128 + d0 + r) * 64 + c;
#pragma unroll
  for (int i = 0; i < 4; i++) {
    ushort4 o;
    o.x = t[c + 4 * i + 0][r];
    o.y = t[c + 4 * i + 1][r];
    o.z = t[c + 4 * i + 2][r];
    o.w = t[c + 4 * i + 3][r];
    reinterpret_cast<ushort4*>(dst)[i] = o;
  }
  if (tt < 64) {
    float s = 0.0f;
#pragma unroll 8
    for (int rr = 0; rr < 64; rr++) {
      union { float f; unsigned int u; } cv;
      cv.u = ((unsigned int)t[rr][tt]) << 16;
      s += cv.f;
    }
    Tsum[((size_t)b * 32 + st) * 128 + d0 + tt] = s;
  }
}

// SufV[b][t][d] = sum_{t' >= t} Tsum[b][t'][d]; SufV[b][32][d] = 0
__global__ void sufB(const float* __restrict__ Tsum, float* __restrict__ SufV) {
  const int b = blockIdx.x;
  const int d = threadIdx.x;
  float v[32];
#pragma unroll
  for (int t = 0; t < 32; t++) v[t] = Tsum[((size_t)b * 32 + t) * 128 + d];
  float run = 0.0f;
  SufV[((size_t)b * 33 + 32) * 128 + d] = 0.0f;
#pragma unroll
  for (int t = 31; t >= 0; t--) {
    run += v[t];
    SufV[((size_t)b * 33 + t) * 128 + d] = run;
  }
}

// ---------------- attention kernel ----------------

#define AS1 __attribute__((address_space(1)))
#define AS3 __attribute__((address_space(3)))

DEVI short8 ldK(const char* ldsK, int row, int off) {
  int addr = row * 256 + (off ^ ((row & 15) << 4));
  return *reinterpret_cast<const short8*>(ldsK + addr);
}
DEVI short8 ldV(const char* ldsV, int row, int off) {
  int addr = row * 128 + (off ^ ((row & 7) << 4));
  return *reinterpret_cast<const short8*>(ldsV + addr);
}

// fixed-max tile body: P = 2^(s-8); no max tracking, no rescale  (R9-verified)
template <bool MASK>
DEVI void tile_body(const char* cb, const short8* qf, f32x16 (&acc)[4],
                    float& l_run, const int ln31, const int h, const int kh,
                    const int qrow, const int kvb) {
  f32x16 sT;
#pragma unroll
  for (int r = 0; r < 16; r++) sT[r] = 0.0f;
  __builtin_amdgcn_s_setprio(1);
#pragma unroll
  for (int kf = 0; kf < 8; kf++) {
    short8 af = ldK(cb, ln31 + 32 * kh, 32 * kf + 16 * h);
    sT = __builtin_amdgcn_mfma_f32_32x32x16_bf16(af, qf[kf], sT, 0, 0, 0);
  }
  __builtin_amdgcn_s_setprio(0);
  if (MASK) {
#pragma unroll
    for (int r = 0; r < 16; r++) {
      int kvg = kvb + (r & 3) + 8 * (r >> 2) + 4 * h;
      if (kvg > qrow) sT[r] = 0.0f;  // multiplicative mask; exp gives 2^-8
    }
  }
#pragma unroll
  for (int r = 0; r < 16; r++) sT[r] = EXP2(sT[r] - MFIX);
  float ts[8];
#pragma unroll
  for (int r = 0; r < 8; r++) ts[r] = sT[r] + sT[r + 8];
#pragma unroll
  for (int r = 0; r < 4; r++) ts[r] = ts[r] + ts[r + 4];
  float sum = (ts[0] + ts[1]) + (ts[2] + ts[3]);
  sum = xhalf_sum(sum);
  l_run += sum;
  // pack P -> bf16 A-fragments: u[0]={a.lo|b.lo}, u[2]={a.hi|b.hi} (R4-verified)
#pragma unroll
  for (int kl = 0; kl < 2; kl++) {
    const int ra = 8 * kl;
    const int rb = 8 * kl + 4;
    unsigned int a0 = cvtpk(sT[ra + 0], sT[ra + 1]);
    unsigned int a1 = cvtpk(sT[ra + 2], sT[ra + 3]);
    unsigned int b0 = cvtpk(sT[rb + 0], sT[rb + 1]);
    unsigned int b1 = cvtpk(sT[rb + 2], sT[rb + 3]);
    plswap(a0, b0);
    plswap(a1, b1);
    union { short8 v; unsigned int u[4]; } pa;
    pa.u[0] = a0; pa.u[1] = a1; pa.u[2] = b0; pa.u[3] = b1;
    const int vboff = 64 * kh + 32 * kl + 16 * h;
    __builtin_amdgcn_s_setprio(1);
#pragma unroll
    for (int nt = 0; nt < 4; nt++) {
      short8 vb = ldV(cb + 16384, ln31 + 32 * nt, vboff);
      acc[nt] = __builtin_amdgcn_mfma_f32_32x32x16_bf16(pa.v, vb, acc[nt], 0, 0, 0);
    }
    __builtin_amdgcn_s_setprio(0);
  }
}

// LDS: 2 buffers x (K 16KB + V 16KB) = 64KB -> 2 blocks/CU.
// Epilogue overlay: 2 qh x 32 rows x 128 f32 = 32KB over buffer 0, + l at 32KB.
#define SMEM_BYTES 66048

__global__ __launch_bounds__(256, 2) void attn_kernel(
    const float* __restrict__ Q, const unsigned short* __restrict__ Kb,
    const unsigned short* __restrict__ Vt, const float* __restrict__ SufV,
    float* __restrict__ out) {
  __shared__ __align__(16) char smem[SMEM_BYTES];

  const int tid = threadIdx.x;
  const int w = tid >> 6, lane = tid & 63;
  const int ln31 = lane & 31, h = lane >> 5;
  const int kh = w & 1;   // kv half of the tile
  const int qh = w >> 1;  // q half: rows [q0+32*qh, +32)

  // LPT decode: long strips (j=31) first; XCD x owns batches {2x, 2x+1}
  const int bid = blockIdx.x;
  const int x = bid & 7, idx = bid >> 3;
  const int b = 2 * x + (idx & 1);
  const int j = 31 - (idx >> 1);

  const int q0 = j * 64;
  const int kv_end = q0 + 64;
  const int qrow = q0 + 32 * qh + ln31;

  // per-wave staging constants (R8/R9-verified swizzle formulas, imm=0)
  // wave 0,1 -> K halves; wave 2,3 -> V halves
  int off[8];
  const char* tbase;
  int dstpart;
  if (w < 2) {
#pragma unroll
    for (int i = 0; i < 8; i++) {
      int L = (w * 8 + i) * 1024 + lane * 16;
      int row = L >> 8;
      off[i] = row * 256 + ((L & 255) ^ ((row & 15) << 4));
    }
    tbase = (const char*)(Kb + (size_t)b * S_LEN * D_DIM);
    dstpart = w * 8192;
  } else {
#pragma unroll
    for (int i = 0; i < 8; i++) {
      int L = ((w - 2) * 8 + i) * 1024 + lane * 16;
      int row = L >> 7;
      off[i] = (L & ~127) + ((L & 127) ^ ((row & 7) << 4));
    }
    tbase = (const char*)Vt + (size_t)b * (S_LEN * D_DIM * 2);
    dstpart = 16384 + (w - 2) * 8192;
  }

#define STAGE(t, bufb)                                                         \
  do {                                                                         \
    const char* src_ = tbase + (size_t)(t) * 16384;                            \
    const int d0_ = (bufb) + dstpart;                                          \
    _Pragma("unroll")                                                          \
    for (int i = 0; i < 8; i++) {                                              \
      __builtin_amdgcn_global_load_lds((const AS1 unsigned int*)(src_ + off[i]),\
                                       (AS3 unsigned int*)(smem + d0_ + i * 1024),\
                                       16, 0, 0);                              \
    }                                                                          \
  } while (0)

  // Q fragments (B-operand): frag kf element jj <-> d = 16*kf + 8*h + jj
  short8 qf[8];
  {
    const float* qsrc = Q + ((size_t)b * S_LEN + qrow) * D_DIM + 8 * h;
#pragma unroll
    for (int kf = 0; kf < 8; kf++) {
      float4 a = *reinterpret_cast<const float4*>(qsrc + 16 * kf);
      float4 d = *reinterpret_cast<const float4*>(qsrc + 16 * kf + 4);
      union { short8 v; unsigned int u[4]; } q8;
      q8.u[0] = cvtpk(a.x * QSC, a.y * QSC);
      q8.u[1] = cvtpk(a.z * QSC, a.w * QSC);
      q8.u[2] = cvtpk(d.x * QSC, d.y * QSC);
      q8.u[3] = cvtpk(d.z * QSC, d.w * QSC);
      qf[kf] = q8.v;
    }
  }

  f32x16 acc[4];
#pragma unroll
  for (int nt = 0; nt < 4; nt++)
#pragma unroll
    for (int rr = 0; rr < 16; rr++) acc[nt][rr] = 0.0f;
  float l_run = 0.0f;

  STAGE(0, 0);
  __syncthreads();
  int buf = 0;
  for (int kt = 0; kt <= j; kt++) {
    const int bb = buf << 15;
    if (kt < j) {
      STAGE(kt + 1, bb ^ 32768);
      tile_body<false>(smem + bb, qf, acc, l_run, ln31, h, kh, qrow,
                       kt * 64 + 32 * kh);
    } else {
      tile_body<true>(smem + bb, qf, acc, l_run, ln31, h, kh, qrow,
                      kt * 64 + 32 * kh);
    }
    __syncthreads();
    buf ^= 1;
  }

  // epilogue: kh=1 waves write partials; kh=0 waves reduce (plain adds: fixed-max)
  float* pbase = (float*)smem + qh * 4096;  // 32 rows x 128 cols f32
  float* lbase = (float*)(smem + 32768) + qh * 32;
  if (kh == 1) {
#pragma unroll
    for (int nt = 0; nt < 4; nt++)
#pragma unroll
      for (int rr = 0; rr < 16; rr++) {
        int cr = (rr & 3) + 8 * (rr >> 2) + 4 * h;
        pbase[cr * 128 + ln31 + 32 * nt] = acc[nt][rr];
      }
    if (h == 0) lbase[ln31] = l_run;
  }
  __syncthreads();
  if (kh == 0) {
    float l_tot = l_run + lbase[ln31];
    l_tot += (float)(S_LEN - kv_end) * E8;
    const float* sv = SufV + ((size_t)b * 33 + (kv_end >> 6)) * 128;
    float* ob = out + ((size_t)b * S_LEN + q0 + 32 * qh) * D_DIM + ln31;
#pragma unroll
    for (int nt = 0; nt < 4; nt++) {
      float svv = sv[ln31 + 32 * nt];
#pragma unroll
      for (int rr = 0; rr < 16; rr++) {
        int cr = (rr & 3) + 8 * (rr >> 2) + 4 * h;
        float v = acc[nt][rr] + pbase[cr * 128 + ln31 + 32 * nt] + E8 * svv;
        float lq = __shfl(l_tot, cr);
        ob[(size_t)cr * D_DIM + 32 * nt] = v / lq;
      }
    }
  }
}

// ---------------- launcher ----------------

extern "C" void kernel_launch(void* const* d_in, const int* in_sizes, int n_in,
                              void* d_out, int out_size, void* d_ws, size_t ws_size,
                              hipStream_t stream) {
  const float* Q = (const float*)d_in[0];
  const float* K = (const float*)d_in[1];
  const float* V = (const float*)d_in[2];
  float* out = (float*)d_out;

  char* ws = (char*)d_ws;
  unsigned short* Kb = (unsigned short*)ws;                 // 8 MiB
  unsigned short* Vt = Kb + 4194304;                        // 8 MiB (tile-major)
  float* Tsum = (float*)(ws + 16777216);                    // 256 KiB
  float* SufV = Tsum + 65536;                               // 264 KiB

  prep<<<3072, 256, 0, stream>>>(K, V, Kb, Vt, Tsum);
  sufB<<<16, 128, 0, stream>>>(Tsum, SufV);
  attn_kernel<<<512, 256, 0, stream>>>(Q, Kb, Vt, SufV, out);
}